// Round 9
// baseline (307.428 us; speedup 1.0000x reference)
//
#include <hip/hip_runtime.h>
#include <math.h>

// ---------------------------------------------------------------------------
// SALAD forward, round 9:
//  - fused12: B-tile triple-buffered (2-tile prefetch window, vmcnt(5))
//  - sinkhorn: linear-domain (E=exp(p) cached bf16 in LDS; no per-iter exp)
//  - agg+final fused into one kernel (ag stays in LDS)
// B=64, C=768, N=1024, HID=512, L=128, M=64, G=256.
// ---------------------------------------------------------------------------

#define B_SZ   64
#define C_IN   768
#define N_LOC  1024
#define HID    512
#define L_DIM  128
#define M_DIM  64
#define G_DIM  256

typedef unsigned short u16;
typedef __bf16 bf16x8 __attribute__((ext_vector_type(8)));
typedef float f32x4 __attribute__((ext_vector_type(4)));

typedef const __attribute__((address_space(1))) void* gptr_t;
typedef __attribute__((address_space(3))) void* sptr_t;

__device__ __forceinline__ void load_lds16(const void* g, void* l) {
    __builtin_amdgcn_global_load_lds((gptr_t)g, (sptr_t)l, 16, 0, 0);
}

__device__ __forceinline__ u16 f2bf(float f) {  // round-to-nearest-even
    unsigned u = __float_as_uint(f);
    u += 0x7fffu + ((u >> 16) & 1u);
    return (u16)(u >> 16);
}
__device__ __forceinline__ float bf2f(u16 h) {
    return __uint_as_float(((unsigned)h) << 16);
}

__device__ __forceinline__ float waveReduceSum(float v) {
#pragma unroll
    for (int off = 32; off > 0; off >>= 1) v += __shfl_xor(v, off, 64);
    return v;
}

// ---------------------------------------------------------------------------
// Weight prep (one launch; packs W1 -> [kt][kc][c][8], W2 -> [k2][kc][c][8]).
// ---------------------------------------------------------------------------
__global__ __launch_bounds__(256) void prep_weights(
        const float* __restrict__ cw1, const float* __restrict__ sw1,
        const float* __restrict__ cw2, const float* __restrict__ sw2,
        u16* __restrict__ cw1p, u16* __restrict__ sw1p,
        u16* __restrict__ cw2p, u16* __restrict__ sw2p) {
    const int q = blockIdx.x * 256 + threadIdx.x;
    const float* src;
    u16* dst;
    if (q < 98304) {                       // W1: 2 x 24 x 4 x 512 chunks
        int path = q / 49152, r = q % 49152;
        int kt = r / 2048, kc = (r / 512) & 3, c = r & 511;
        src = (path ? sw1 : cw1) + (size_t)c * C_IN + kt * 32 + kc * 8;
        dst = (path ? sw1p : cw1p) + (size_t)r * 8;
    } else {                               // W2: f 8192 + p 4096 chunks
        int q2 = q - 98304;
        int path = (q2 >= 8192) ? 1 : 0;
        int r = q2 - (path ? 8192 : 0);
        int S2 = path ? M_DIM : L_DIM;
        int k2 = r / (4 * S2), kc = (r / S2) & 3, c = r % S2;
        src = (path ? sw2 : cw2) + (size_t)c * HID + k2 * 32 + kc * 8;
        dst = (path ? sw2p : cw2p) + (size_t)r * 8;
    }
    float4 v0 = *(const float4*)(src);
    float4 v1 = *(const float4*)(src + 4);
    *(ushort4*)(dst) = make_ushort4(f2bf(v0.x), f2bf(v0.y), f2bf(v0.z), f2bf(v0.w));
    *(ushort4*)(dst + 4) = make_ushort4(f2bf(v1.x), f2bf(v1.y), f2bf(v1.z), f2bf(v1.w));
}

// ---------------------------------------------------------------------------
// x [B][C][N] fp32 -> xPack bf16 in A-tile LDS image order.
// grid = (N/64, C/64, B), block 256.
// ---------------------------------------------------------------------------
__global__ __launch_bounds__(256) void transpose_x(const float* __restrict__ x,
                                                   u16* __restrict__ xP) {
    __shared__ float tile[64][65];
    const int n0 = blockIdx.x * 64;
    const int c0 = blockIdx.y * 64;
    const size_t b = blockIdx.z;
    const float* xb = x + b * (size_t)(C_IN * N_LOC);
    u16* xpb = xP + b * (size_t)(N_LOC * C_IN);
    const int tid = threadIdx.x;

    const int jn = (tid & 15) * 4;
    const int cr = tid >> 4;
#pragma unroll
    for (int r = 0; r < 4; ++r) {
        int c = cr + r * 16;
        float4 v = *(const float4*)(xb + (size_t)(c0 + c) * N_LOC + n0 + jn);
        tile[c][jn + 0] = v.x;
        tile[c][jn + 1] = v.y;
        tile[c][jn + 2] = v.z;
        tile[c][jn + 3] = v.w;
    }
    __syncthreads();

    const int n = tid & 63;
    const int ch0 = tid >> 6;        // 0..3
    const int nG = n0 + n;
#pragma unroll
    for (int r = 0; r < 2; ++r) {
        const int ch = ch0 + r * 4;          // 0..7
        const int cG = c0 + ch * 8;
        u16* dst = xpb + (size_t)(nG >> 7) * (128 * C_IN) + (cG >> 5) * 4096 +
                   ((cG & 31) >> 3) * 1024 + (nG & 127) * 8;
        ushort4 o0 = make_ushort4(f2bf(tile[ch * 8 + 0][n]), f2bf(tile[ch * 8 + 1][n]),
                                  f2bf(tile[ch * 8 + 2][n]), f2bf(tile[ch * 8 + 3][n]));
        ushort4 o1 = make_ushort4(f2bf(tile[ch * 8 + 4][n]), f2bf(tile[ch * 8 + 5][n]),
                                  f2bf(tile[ch * 8 + 6][n]), f2bf(tile[ch * 8 + 7][n]));
        *(ushort4*)(dst) = o0;
        *(ushort4*)(dst + 4) = o1;
    }
}

// ---------------------------------------------------------------------------
// Fused stage-1 + stage-2 (packed staging, B triple-buffered).
// LDS: A[2][4096 u16] at 0; B[3][16384 u16] at 8192 (112 KiB live);
//      h handoff reuses full 128 KiB union.
// tile t (A buf db=t&1, B buf bc=t%3):
//   ph0 {read av+bwl | STG_B(t+2 -> (t+2)%3) | MFMA ni 0..3}
//   ph1 {read bwh    | STG_A(t+2 -> db)      | MFMA ni 4..7}
//   boundary vmcnt(5) (B(t+2):4 + A(t+2):1 in flight), barrier.
// grid (8, 2, 64) XCD-bijective remap; 512 threads.
// ---------------------------------------------------------------------------
__global__ __launch_bounds__(512, 2) void fused12(
        const u16* __restrict__ xP,
        const u16* __restrict__ cw1p, const float* __restrict__ cb1,
        const u16* __restrict__ cw2p, const float* __restrict__ cb2,
        const u16* __restrict__ sw1p, const float* __restrict__ sb1,
        const u16* __restrict__ sw2p, const float* __restrict__ sb2,
        u16* __restrict__ fT, u16* __restrict__ pT) {
    __shared__ __align__(16) u16 LDSu[65536];   // 128 KiB union
    const int tid = threadIdx.x;
    const int lane = tid & 63;
    const int wid = tid >> 6;
    const int wr = wid >> 2;   // 0..1 : row half (64 rows)
    const int wc = wid & 3;    // 0..3 : col quarter (128 cols)

    const int id = blockIdx.x + 8 * blockIdx.y + 16 * blockIdx.z;
    const int nid = (id & 7) * 128 + (id >> 3);   // 1024 % 8 == 0, bijective
    const int bx = nid & 7;
    const int path = (nid >> 3) & 1;
    const int bz = nid >> 4;
    const int r0 = bx * 128;

    const u16* W1p = path ? sw1p : cw1p;
    const float* B1 = path ? sb1 : cb1;
    const u16* W2p = path ? sw2p : cw2p;
    const float* B2 = path ? sb2 : cb2;
    u16* O2 = path ? pT : fT;
    const int S2 = path ? M_DIM : L_DIM;

    const u16* Ap = xP + (size_t)bz * N_LOC * C_IN + (size_t)bx * (128 * C_IN);

    f32x4 acc1[4][8];
#pragma unroll
    for (int mi = 0; mi < 4; ++mi)
#pragma unroll
        for (int ni = 0; ni < 8; ++ni)
            acc1[mi][ni] = (f32x4){0.f, 0.f, 0.f, 0.f};

    const int nk = C_IN / 32;   // 24

#define STG_A(db_, kt_)                                                        \
    load_lds16(Ap + (size_t)(kt_) * 4096 + tid * 8, &LDSu[(db_) * 4096 + tid * 8])
#define STG_B(bb_, kt_)                                                        \
    do {                                                                       \
        _Pragma("unroll")                                                      \
        for (int j_ = 0; j_ < 4; ++j_)                                         \
            load_lds16(W1p + (size_t)(kt_) * 16384 + (size_t)(j_ * 512 + tid) * 8, \
                       &LDSu[8192 + (bb_) * 16384 + (j_ * 512 + tid) * 8]);    \
    } while (0)

#define AV_PTR(db_, mi_)                                                       \
    ((const bf16x8*)&LDSu[(db_) * 4096 + (lane >> 4) * 1024 +                  \
                          (64 * wr + 16 * (mi_) + (lane & 15)) * 8])
#define BW_PTR(bb_, ni_)                                                       \
    ((const bf16x8*)&LDSu[8192 + (bb_) * 16384 + (lane >> 4) * 4096 +          \
                          (128 * wc + 16 * (ni_) + (lane & 15)) * 8])

#define PHASE_MID()                                                            \
    __builtin_amdgcn_s_barrier();                                              \
    asm volatile("s_waitcnt lgkmcnt(0)" ::: "memory");                         \
    __builtin_amdgcn_sched_barrier(0);                                         \
    __builtin_amdgcn_s_setprio(1)

#define PHASE_END()                                                            \
    __builtin_amdgcn_s_setprio(0);                                             \
    __builtin_amdgcn_sched_barrier(0);                                         \
    __builtin_amdgcn_s_barrier()

    // prologue: A0,B0,A1,B1 issued; vmcnt(5) retires A0+B0, leaves A1+B1.
    STG_A(0, 0);
    STG_B(0, 0);
    STG_A(1, 1);
    STG_B(1, 1);
    asm volatile("s_waitcnt vmcnt(5)" ::: "memory");
    __builtin_amdgcn_s_barrier();

    for (int t = 0; t < nk; ++t) {
        const int db = t & 1;
        const int bc = t % 3;
        const int bs = (bc + 2 >= 3) ? bc - 1 : bc + 2;   // (t+2)%3
        bf16x8 av[4], bwl[4], bwh[4];

        // ---- phase 0 : cols ni 0..3
#pragma unroll
        for (int mi = 0; mi < 4; ++mi) av[mi] = *AV_PTR(db, mi);
#pragma unroll
        for (int ni = 0; ni < 4; ++ni) bwl[ni] = *BW_PTR(bc, ni);
        if (t + 2 < nk) STG_B(bs, t + 2);
        PHASE_MID();
#pragma unroll
        for (int mi = 0; mi < 4; ++mi)
#pragma unroll
            for (int ni = 0; ni < 4; ++ni)
                acc1[mi][ni] = __builtin_amdgcn_mfma_f32_16x16x32_bf16(
                    av[mi], bwl[ni], acc1[mi][ni], 0, 0, 0);
        PHASE_END();

        // ---- phase 1 : cols ni 4..7 (av reused from registers)
#pragma unroll
        for (int ni = 0; ni < 4; ++ni) bwh[ni] = *BW_PTR(bc, 4 + ni);
        if (t + 2 < nk) STG_A(db, t + 2);
        PHASE_MID();
#pragma unroll
        for (int mi = 0; mi < 4; ++mi)
#pragma unroll
            for (int ni = 0; ni < 4; ++ni)
                acc1[mi][4 + ni] = __builtin_amdgcn_mfma_f32_16x16x32_bf16(
                    av[mi], bwh[ni], acc1[mi][4 + ni], 0, 0, 0);
        __builtin_amdgcn_s_setprio(0);
        __builtin_amdgcn_sched_barrier(0);
        if (t + 2 < nk)
            asm volatile("s_waitcnt vmcnt(5)" ::: "memory");
        else
            asm volatile("s_waitcnt vmcnt(0)" ::: "memory");
        __builtin_amdgcn_s_barrier();
    }
#undef STG_A
#undef STG_B
#undef AV_PTR
#undef BW_PTR
#undef PHASE_MID
#undef PHASE_END

    // ---- handoff: bias+relu, h -> LDS as [64 cchunk][128 n][8] bf16
    {
        float bv1[8];
#pragma unroll
        for (int ni = 0; ni < 8; ++ni)
            bv1[ni] = B1[128 * wc + 16 * ni + (lane & 15)];
#pragma unroll
        for (int mi = 0; mi < 4; ++mi)
#pragma unroll
            for (int ni = 0; ni < 8; ++ni)
#pragma unroll
                for (int rr = 0; rr < 4; ++rr) {
                    int n = 64 * wr + 16 * mi + (lane >> 4) * 4 + rr;
                    int c = 128 * wc + 16 * ni + (lane & 15);
                    float v = fmaxf(acc1[mi][ni][rr] + bv1[ni], 0.f);
                    LDSu[(c >> 3) * 1024 + n * 8 + (c & 7)] = f2bf(v);
                }
    }
    __syncthreads();

    // ---- stage-2: Out2 = h . W2^T + b2, K=512 in 16 chunks of 32.
    f32x4 acc2[4][2];
#pragma unroll
    for (int mi = 0; mi < 4; ++mi) {
        acc2[mi][0] = (f32x4){0.f, 0.f, 0.f, 0.f};
        acc2[mi][1] = (f32x4){0.f, 0.f, 0.f, 0.f};
    }
    const int c2base = (S2 == L_DIM) ? 32 * wc : 16 * wc;
    const int cA = c2base + (lane & 15);
    const int cB = c2base + 16 + (lane & 15);   // f-path only
    const int fb0 = (lane >> 4) * S2 + cA;      // packed fragment index
    const int fb1 = (lane >> 4) * S2 + cB;

    bf16x8 w0n = *(const bf16x8*)(W2p + (size_t)fb0 * 8);
    bf16x8 w1n = {};
    if (S2 == L_DIM) w1n = *(const bf16x8*)(W2p + (size_t)fb1 * 8);

    for (int k2 = 0; k2 < 16; ++k2) {
        bf16x8 w0 = w0n, w1 = w1n;
        if (k2 < 15) {
            w0n = *(const bf16x8*)(W2p + ((size_t)(k2 + 1) * 4 * S2 + fb0) * 8);
            if (S2 == L_DIM)
                w1n = *(const bf16x8*)(W2p + ((size_t)(k2 + 1) * 4 * S2 + fb1) * 8);
        }
        bf16x8 a2[4];
#pragma unroll
        for (int mi = 0; mi < 4; ++mi)
            a2[mi] = *(const bf16x8*)&LDSu[(k2 * 4 + (lane >> 4)) * 1024 +
                                           (64 * wr + 16 * mi + (lane & 15)) * 8];
#pragma unroll
        for (int mi = 0; mi < 4; ++mi) {
            acc2[mi][0] = __builtin_amdgcn_mfma_f32_16x16x32_bf16(
                a2[mi], w0, acc2[mi][0], 0, 0, 0);
            if (S2 == L_DIM)
                acc2[mi][1] = __builtin_amdgcn_mfma_f32_16x16x32_bf16(
                    a2[mi], w1, acc2[mi][1], 0, 0, 0);
        }
    }

    const float b20 = B2[cA];
    const float b21 = (S2 == L_DIM) ? B2[cB] : 0.f;
    u16* Ob = O2 + (size_t)bz * N_LOC * S2;
#pragma unroll
    for (int mi = 0; mi < 4; ++mi)
#pragma unroll
        for (int rr = 0; rr < 4; ++rr) {
            int row = r0 + 64 * wr + 16 * mi + (lane >> 4) * 4 + rr;
            Ob[(size_t)row * S2 + cA] = f2bf(acc2[mi][0][rr] + b20);
            if (S2 == L_DIM)
                Ob[(size_t)row * S2 + cB] = f2bf(acc2[mi][1][rr] + b21);
        }
}

// ---------------------------------------------------------------------------
// Token MLP stage 1: hidb[b][j] = relu(t[b] . tw1[j] + tb1[j]); grid (8,B).
// ---------------------------------------------------------------------------
__global__ __launch_bounds__(256) void tok1_kernel(const float* __restrict__ t,
                                                   const float* __restrict__ tw1,
                                                   const float* __restrict__ tb1,
                                                   float* __restrict__ hidb) {
    __shared__ __align__(16) float tl[C_IN];
    const int b = blockIdx.y;
    const int j0 = blockIdx.x * 64;
    const int tid = threadIdx.x;
    const int lane = tid & 63;
    const int wave = tid >> 6;
    for (int i = tid; i < C_IN; i += 256) tl[i] = t[(size_t)b * C_IN + i];
    __syncthreads();
    for (int j = wave; j < 64; j += 4) {
        const int row = j0 + j;
        const float4* wr = (const float4*)(tw1 + (size_t)row * C_IN);
        const float4* tr = (const float4*)tl;
        float s = 0.f;
#pragma unroll
        for (int q = 0; q < 3; ++q) {
            float4 wv = wr[lane + 64 * q];
            float4 tv = tr[lane + 64 * q];
            s += wv.x * tv.x + wv.y * tv.y + wv.z * tv.z + wv.w * tv.w;
        }
        s = waveReduceSum(s);
        if (lane == 0) hidb[(size_t)b * HID + row] = fmaxf(s + tb1[row], 0.f);
    }
}

// ---------------------------------------------------------------------------
// Token MLP stage 2: tok[b][g] = hidb[b] . tw2[g] + tb2[g]; grid (4,B).
// ---------------------------------------------------------------------------
__global__ __launch_bounds__(256) void tok2_kernel(const float* __restrict__ hidb,
                                                   const float* __restrict__ tw2,
                                                   const float* __restrict__ tb2,
                                                   float* __restrict__ tok) {
    __shared__ __align__(16) float hl[HID];
    const int b = blockIdx.y;
    const int g0 = blockIdx.x * 64;
    const int tid = threadIdx.x;
    const int lane = tid & 63;
    const int wave = tid >> 6;
    for (int i = tid; i < HID; i += 256) hl[i] = hidb[(size_t)b * HID + i];
    __syncthreads();
    for (int j = wave; j < 64; j += 4) {
        const int row = g0 + j;
        const float4* wr = (const float4*)(tw2 + (size_t)row * HID);
        const float4* hr = (const float4*)hl;
        float s = 0.f;
#pragma unroll
        for (int q = 0; q < 2; ++q) {
            float4 wv = wr[lane + 64 * q];
            float4 hv = hr[lane + 64 * q];
            s += wv.x * hv.x + wv.y * hv.y + wv.z * hv.z + wv.w * hv.w;
        }
        s = waveReduceSum(s);
        if (lane == 0) tok[(size_t)b * G_DIM + row] = s + tb2[row];
    }
}

// ---------------------------------------------------------------------------
// Sinkhorn, linear domain: E = exp(p) cached bf16 in LDS (in place of p);
//   eu[m] = mu_m / sum_n E[m][n] ev[n];  ev[n] = nu / (sum_m E[m][n] eu[m]
//   + Ea*eu[64]);  P = E * eu * ev * 1088.
// One block (1024 thr) per batch. No per-iteration exp.
// ---------------------------------------------------------------------------
__global__ __launch_bounds__(1024) void sinkhorn_kernel(const u16* __restrict__ pT,
                                                        const float* __restrict__ dust,
                                                        float* __restrict__ PT) {
    __shared__ u16 sp[M_DIM][N_LOC];   // holds E = exp(p), bf16
    __shared__ float eu[M_DIM + 1];
    __shared__ float ev[N_LOC];
    const int b = blockIdx.x;
    const int t = threadIdx.x;
    const int lane = t & 63;
    const int wave = t >> 6;
    const float alpha = dust[0];
    const float Ea = __expf(alpha);
    const float mu = 1.f / 1088.f;        // exp(norm), norm = -log(m+n)
    const float mu64 = 960.f / 1088.f;    // exp(log(n-m)+norm)
    const float nu = 1.f / 1088.f;

    // stage p column t, then convert in place to E = exp(p)
    const uint4* prow = (const uint4*)(pT + ((size_t)b * N_LOC + t) * M_DIM);
#pragma unroll
    for (int q = 0; q < 8; ++q) {
        uint4 ch = prow[q];
        sp[q * 8 + 0][t] = (u16)(ch.x);
        sp[q * 8 + 1][t] = (u16)(ch.x >> 16);
        sp[q * 8 + 2][t] = (u16)(ch.y);
        sp[q * 8 + 3][t] = (u16)(ch.y >> 16);
        sp[q * 8 + 4][t] = (u16)(ch.z);
        sp[q * 8 + 5][t] = (u16)(ch.z >> 16);
        sp[q * 8 + 6][t] = (u16)(ch.w);
        sp[q * 8 + 7][t] = (u16)(ch.w >> 16);
    }
#pragma unroll
    for (int m = 0; m < M_DIM; ++m)
        sp[m][t] = f2bf(__expf(bf2f(sp[m][t])));
    ev[t] = 1.f;
    __syncthreads();

    for (int it = 0; it < 3; ++it) {
        // eu[m] = mu_m / sum_n E[m][n] * ev[n]
        for (int m = wave; m < M_DIM + 1; m += 16) {
            float s = 0.f;
            if (m < M_DIM) {
#pragma unroll
                for (int q = 0; q < 16; ++q) {
                    int c = lane + 64 * q;
                    s += bf2f(sp[m][c]) * ev[c];
                }
            } else {
#pragma unroll
                for (int q = 0; q < 16; ++q) {
                    int c = lane + 64 * q;
                    s += ev[c];
                }
                s *= Ea;
            }
            s = waveReduceSum(s);
            if (lane == 0) eu[m] = ((m < M_DIM) ? mu : mu64) / s;
        }
        __syncthreads();
        // ev[n] = nu / (sum_m E[m][n] * eu[m] + Ea * eu[64])
        float s = Ea * eu[M_DIM];
#pragma unroll 8
        for (int m = 0; m < M_DIM; ++m) s += bf2f(sp[m][t]) * eu[m];
        ev[t] = nu / s;
        __syncthreads();
    }

    const float evt = ev[t] * 1088.f;
    float* Prow = PT + ((size_t)b * N_LOC + t) * M_DIM;
#pragma unroll
    for (int m4 = 0; m4 < M_DIM; m4 += 4) {
        float4 o;
        o.x = bf2f(sp[m4 + 0][t]) * eu[m4 + 0] * evt;
        o.y = bf2f(sp[m4 + 1][t]) * eu[m4 + 1] * evt;
        o.z = bf2f(sp[m4 + 2][t]) * eu[m4 + 2] * evt;
        o.w = bf2f(sp[m4 + 3][t]) * eu[m4 + 3] * evt;
        *(float4*)(Prow + m4) = o;
    }
}

// ---------------------------------------------------------------------------
// Fused agg + normalization cascade. One block (512 thr) per batch.
// agg[l][m] = sum_n fT[b,n,l] * PT[b,n,m] -> ag LDS; then per-m norm over l,
// tok norm, concat, global L2 norm, write out.
// ---------------------------------------------------------------------------
__global__ __launch_bounds__(512) void agg_final_kernel(const u16* __restrict__ fT,
                                                        const float* __restrict__ PT,
                                                        const float* __restrict__ tok,
                                                        float* __restrict__ out) {
    __shared__ __align__(16) float Fs[64][L_DIM];    // 32 KB
    __shared__ __align__(16) float Ps[64][M_DIM];    // 16 KB
    __shared__ __align__(16) float ag[L_DIM * M_DIM];// 32 KB
    __shared__ float rm[M_DIM];
    __shared__ float red[8];
    __shared__ float tk[G_DIM];
    const int b = blockIdx.x;
    const int tid = threadIdx.x;
    const int lane = tid & 63;
    const int wave = tid >> 6;
    const float EPS = 1e-12f;
    const u16* fb = fT + (size_t)b * N_LOC * L_DIM;
    const float* Pb = PT + (size_t)b * N_LOC * M_DIM;
    const int m0 = (tid & 15) * 4;
    const int l0 = (tid >> 4) * 4;

    if (tid < G_DIM) tk[tid] = tok[(size_t)b * G_DIM + tid];

    float acc[4][4] = {};
    for (int n0 = 0; n0 < N_LOC; n0 += 64) {
        __syncthreads();
#pragma unroll
        for (int pass = 0; pass < 2; ++pass) {
            int idx = pass * 512 + tid;
            int nn = idx >> 4, cc = (idx & 15) * 8;
            const u16* src = fb + (size_t)(n0 + nn) * L_DIM + cc;
            ushort4 h0 = *(const ushort4*)(src);
            ushort4 h1 = *(const ushort4*)(src + 4);
            Fs[nn][cc + 0] = bf2f(h0.x); Fs[nn][cc + 1] = bf2f(h0.y);
            Fs[nn][cc + 2] = bf2f(h0.z); Fs[nn][cc + 3] = bf2f(h0.w);
            Fs[nn][cc + 4] = bf2f(h1.x); Fs[nn][cc + 5] = bf2f(h1.y);
            Fs[nn][cc + 6] = bf2f(h1.z); Fs[nn][cc + 7] = bf2f(h1.w);
        }
#pragma unroll
        for (int pass = 0; pass < 2; ++pass) {
            int idx = pass * 512 + tid;
            int nn = idx >> 4, cc = (idx & 15) * 4;
            float4 vv = *(const float4*)(Pb + (size_t)(n0 + nn) * M_DIM + cc);
            *(float4*)&Ps[nn][cc] = vv;
        }
        __syncthreads();
#pragma unroll 8
        for (int nn = 0; nn < 64; ++nn) {
            float4 a = *(const float4*)(&Fs[nn][l0]);
            float4 bb = *(const float4*)(&Ps[nn][m0]);
            float av[4] = {a.x, a.y, a.z, a.w};
            float bv[4] = {bb.x, bb.y, bb.z, bb.w};
#pragma unroll
            for (int i = 0; i < 4; ++i)
#pragma unroll
                for (int j = 0; j < 4; ++j)
                    acc[i][j] = fmaf(av[i], bv[j], acc[i][j]);
        }
    }

#pragma unroll
    for (int i = 0; i < 4; ++i)
#pragma unroll
        for (int j = 0; j < 4; ++j)
            ag[(l0 + i) * M_DIM + m0 + j] = acc[i][j];
    __syncthreads();

    // per-m norms over l
    if (tid < M_DIM) {
        float ss = 0.f;
#pragma unroll 8
        for (int l = 0; l < L_DIM; ++l) {
            float x = ag[l * M_DIM + tid];
            ss = fmaf(x, x, ss);
        }
        rm[tid] = 1.f / fmaxf(sqrtf(ss), EPS);
    }
    // tok sumsq
    const float tv = (tid < G_DIM) ? tk[tid] : 0.f;
    float ssl = tv * tv;
    ssl = waveReduceSum(ssl);
    if (lane == 0) red[wave] = ssl;
    __syncthreads();
    float stok = 0.f;
#pragma unroll
    for (int w = 0; w < 8; ++w) stok += red[w];
    const float rt = 1.f / fmaxf(sqrtf(stok), EPS);
    const float tn = tv * rt;

    // global sumsq
    float gs = (tid < G_DIM) ? tn * tn : 0.f;
    for (int e = tid; e < L_DIM * M_DIM; e += 512) {
        float x = ag[e] * rm[e & (M_DIM - 1)];
        gs = fmaf(x, x, gs);
    }
    __syncthreads();   // red reuse
    gs = waveReduceSum(gs);
    if (lane == 0) red[wave] = gs;
    __syncthreads();
    float G = 0.f;
#pragma unroll
    for (int w = 0; w < 8; ++w) G += red[w];
    const float rg = 1.f / fmaxf(sqrtf(G), EPS);

    float* ob = out + (size_t)b * (G_DIM + L_DIM * M_DIM);
    if (tid < G_DIM) ob[tid] = tn * rg;
    for (int e = tid; e < L_DIM * M_DIM; e += 512)
        ob[G_DIM + e] = ag[e] * rm[e & (M_DIM - 1)] * rg;
}

// ---------------------------------------------------------------------------
extern "C" void kernel_launch(void* const* d_in, const int* in_sizes, int n_in,
                              void* d_out, int out_size, void* d_ws, size_t ws_size,
                              hipStream_t stream) {
    const float* x    = (const float*)d_in[0];
    const float* t    = (const float*)d_in[1];
    const float* tw1  = (const float*)d_in[2];
    const float* tb1  = (const float*)d_in[3];
    const float* tw2  = (const float*)d_in[4];
    const float* tb2  = (const float*)d_in[5];
    const float* cw1  = (const float*)d_in[6];
    const float* cb1  = (const float*)d_in[7];
    const float* cw2  = (const float*)d_in[8];
    const float* cb2  = (const float*)d_in[9];
    const float* sw1  = (const float*)d_in[10];
    const float* sb1  = (const float*)d_in[11];
    const float* sw2  = (const float*)d_in[12];
    const float* sb2  = (const float*)d_in[13];
    const float* dust = (const float*)d_in[14];
    float* out = (float*)d_out;

    char* ws = (char*)d_ws;
    u16* xP    = (u16*)(ws);                         // 100,663,296
    u16* fT    = (u16*)(ws + 100663296ull);          //  16,777,216
    u16* pT    = (u16*)(ws + 117440512ull);          //   8,388,608
    u16* cw1p  = (u16*)(ws + 125829120ull);          //     786,432
    u16* sw1p  = (u16*)(ws + 126615552ull);          //     786,432
    u16* cw2p  = (u16*)(ws + 127401984ull);          //     131,072
    u16* sw2p  = (u16*)(ws + 127533056ull);          //      65,536
    float* hidb = (float*)(ws + 127598592ull);       //     131,072
    // reuse of dead xP region after fused12:
    float* PT     = (float*)(ws);                    //  16,777,216
    float* tokbuf = (float*)(ws + 20971520ull);      //      65,536

    prep_weights<<<432, 256, 0, stream>>>(cw1, sw1, cw2, sw2,
                                          cw1p, sw1p, cw2p, sw2p);
    transpose_x<<<dim3(N_LOC / 64, C_IN / 64, B_SZ), 256, 0, stream>>>(x, xP);

    fused12<<<dim3(8, 2, B_SZ), 512, 0, stream>>>(
        xP, cw1p, cb1, cw2p, cb2, sw1p, sb1, sw2p, sb2, fT, pT);

    tok1_kernel<<<dim3(HID / 64, B_SZ), 256, 0, stream>>>(t, tw1, tb1, hidb);
    tok2_kernel<<<dim3(G_DIM / 64, B_SZ), 256, 0, stream>>>(hidb, tw2, tb2, tokbuf);

    sinkhorn_kernel<<<B_SZ, 1024, 0, stream>>>(pT, dust, PT);
    agg_final_kernel<<<B_SZ, 512, 0, stream>>>(fT, PT, tokbuf, out);
}

// Round 10
// 291.471 us; speedup vs baseline: 1.0547x; 1.0547x over previous
//
#include <hip/hip_runtime.h>
#include <math.h>

// ---------------------------------------------------------------------------
// SALAD forward, round 10:
//  - fused12: BK=64 (12 K-tiles), kk-split phases (32 MFMA/phase), dbuf LDS
//    160 KiB exactly; staging of t+1 issued at ph0(t), drained at boundary.
//    Half the barriers of round 8/9. Pack layouts unchanged (invariant).
//  - agg/final reverted to round-8 split (256-block agg + 64-block final).
//  - linear-domain sinkhorn kept (round 9, verified).
// B=64, C=768, N=1024, HID=512, L=128, M=64, G=256.
// ---------------------------------------------------------------------------

#define B_SZ   64
#define C_IN   768
#define N_LOC  1024
#define HID    512
#define L_DIM  128
#define M_DIM  64
#define G_DIM  256

typedef unsigned short u16;
typedef __bf16 bf16x8 __attribute__((ext_vector_type(8)));
typedef float f32x4 __attribute__((ext_vector_type(4)));

typedef const __attribute__((address_space(1))) void* gptr_t;
typedef __attribute__((address_space(3))) void* sptr_t;

__device__ __forceinline__ void load_lds16(const void* g, void* l) {
    __builtin_amdgcn_global_load_lds((gptr_t)g, (sptr_t)l, 16, 0, 0);
}

__device__ __forceinline__ u16 f2bf(float f) {  // round-to-nearest-even
    unsigned u = __float_as_uint(f);
    u += 0x7fffu + ((u >> 16) & 1u);
    return (u16)(u >> 16);
}
__device__ __forceinline__ float bf2f(u16 h) {
    return __uint_as_float(((unsigned)h) << 16);
}

__device__ __forceinline__ float waveReduceSum(float v) {
#pragma unroll
    for (int off = 32; off > 0; off >>= 1) v += __shfl_xor(v, off, 64);
    return v;
}

// ---------------------------------------------------------------------------
// Weight prep (one launch; packs W1 -> [kchunk][c][8], W2 -> [k2][kc][c][8]).
// Layout is BK-invariant: u16 offset = ((k>>3)*512 + c)*8 for W1.
// ---------------------------------------------------------------------------
__global__ __launch_bounds__(256) void prep_weights(
        const float* __restrict__ cw1, const float* __restrict__ sw1,
        const float* __restrict__ cw2, const float* __restrict__ sw2,
        u16* __restrict__ cw1p, u16* __restrict__ sw1p,
        u16* __restrict__ cw2p, u16* __restrict__ sw2p) {
    const int q = blockIdx.x * 256 + threadIdx.x;
    const float* src;
    u16* dst;
    if (q < 98304) {                       // W1: 2 x 96 kchunk x 512 c
        int path = q / 49152, r = q % 49152;
        int kch = r / 512, c = r & 511;
        src = (path ? sw1 : cw1) + (size_t)c * C_IN + kch * 8;
        dst = (path ? sw1p : cw1p) + (size_t)r * 8;
    } else {                               // W2: f 8192 + p 4096 chunks
        int q2 = q - 98304;
        int path = (q2 >= 8192) ? 1 : 0;
        int r = q2 - (path ? 8192 : 0);
        int S2 = path ? M_DIM : L_DIM;
        int k2 = r / (4 * S2), kc = (r / S2) & 3, c = r % S2;
        src = (path ? sw2 : cw2) + (size_t)c * HID + k2 * 32 + kc * 8;
        dst = (path ? sw2p : cw2p) + (size_t)r * 8;
    }
    float4 v0 = *(const float4*)(src);
    float4 v1 = *(const float4*)(src + 4);
    *(ushort4*)(dst) = make_ushort4(f2bf(v0.x), f2bf(v0.y), f2bf(v0.z), f2bf(v0.w));
    *(ushort4*)(dst + 4) = make_ushort4(f2bf(v1.x), f2bf(v1.y), f2bf(v1.z), f2bf(v1.w));
}

// ---------------------------------------------------------------------------
// x [B][C][N] fp32 -> xPack bf16 in A-tile LDS image order:
//   off(b,n,c) = b*N*C + (n>>7)*(128*C) + (c>>3)*1024 + (n&127)*8 + (c&7)
// (BK-invariant). grid = (N/64, C/64, B), block 256.
// ---------------------------------------------------------------------------
__global__ __launch_bounds__(256) void transpose_x(const float* __restrict__ x,
                                                   u16* __restrict__ xP) {
    __shared__ float tile[64][65];
    const int n0 = blockIdx.x * 64;
    const int c0 = blockIdx.y * 64;
    const size_t b = blockIdx.z;
    const float* xb = x + b * (size_t)(C_IN * N_LOC);
    u16* xpb = xP + b * (size_t)(N_LOC * C_IN);
    const int tid = threadIdx.x;

    const int jn = (tid & 15) * 4;
    const int cr = tid >> 4;
#pragma unroll
    for (int r = 0; r < 4; ++r) {
        int c = cr + r * 16;
        float4 v = *(const float4*)(xb + (size_t)(c0 + c) * N_LOC + n0 + jn);
        tile[c][jn + 0] = v.x;
        tile[c][jn + 1] = v.y;
        tile[c][jn + 2] = v.z;
        tile[c][jn + 3] = v.w;
    }
    __syncthreads();

    const int n = tid & 63;
    const int ch0 = tid >> 6;        // 0..3
    const int nG = n0 + n;
#pragma unroll
    for (int r = 0; r < 2; ++r) {
        const int ch = ch0 + r * 4;          // 0..7
        const int cG = c0 + ch * 8;
        u16* dst = xpb + (size_t)(nG >> 7) * (128 * C_IN) + (cG >> 3) * 1024 +
                   (nG & 127) * 8;
        ushort4 o0 = make_ushort4(f2bf(tile[ch * 8 + 0][n]), f2bf(tile[ch * 8 + 1][n]),
                                  f2bf(tile[ch * 8 + 2][n]), f2bf(tile[ch * 8 + 3][n]));
        ushort4 o1 = make_ushort4(f2bf(tile[ch * 8 + 4][n]), f2bf(tile[ch * 8 + 5][n]),
                                  f2bf(tile[ch * 8 + 6][n]), f2bf(tile[ch * 8 + 7][n]));
        *(ushort4*)(dst) = o0;
        *(ushort4*)(dst + 4) = o1;
    }
}

// ---------------------------------------------------------------------------
// Fused stage-1 + stage-2, BK=64.
// Stage-1: h[128 n][512 c] = relu(x . W1^T + b1), nk=12 K-tiles.
//   8 waves (2 row-halves x 4 col-quarters), acc1[4][8], 64 MFMA/tile/wave.
//   LDS (160 KiB): A[2][8192 u16] at 0 ([kc8][n128][8]);
//                  B[2][32768 u16] at 16384 ([kc8][c512][8]).
//   tile t (buf db=t&1), kk-split phases:
//     ph0 (kk=0): 12 ds_reads | STG all of t+1 -> db^1 (10 calls)
//                 | barrier,lgkm(0) | 32 MFMA | barrier
//     ph1 (kk=1): 12 ds_reads | barrier,lgkm(0) | 32 MFMA
//                 | vmcnt(0), barrier   (t+1 fully landed; issued 2 phases ago)
// Handoff: h -> LDS [64 cchunk][128 n][8] (128 KiB of the union), syncthreads.
// Stage-2: Out2 = h . W2^T + b2 (K=512), W2 from packed global, 1-deep
//   register prefetch; no barriers.
// grid (8, 2, 64) XCD-bijective remap; 512 threads.
// ---------------------------------------------------------------------------
__global__ __launch_bounds__(512, 2) void fused12(
        const u16* __restrict__ xP,
        const u16* __restrict__ cw1p, const float* __restrict__ cb1,
        const u16* __restrict__ cw2p, const float* __restrict__ cb2,
        const u16* __restrict__ sw1p, const float* __restrict__ sb1,
        const u16* __restrict__ sw2p, const float* __restrict__ sb2,
        u16* __restrict__ fT, u16* __restrict__ pT) {
    __shared__ __align__(16) u16 LDSu[81920];   // 160 KiB
    const int tid = threadIdx.x;
    const int lane = tid & 63;
    const int wid = tid >> 6;
    const int wr = wid >> 2;   // 0..1 : row half (64 rows)
    const int wc = wid & 3;    // 0..3 : col quarter (128 cols)

    const int id = blockIdx.x + 8 * blockIdx.y + 16 * blockIdx.z;
    const int nid = (id & 7) * 128 + (id >> 3);   // 1024 % 8 == 0, bijective
    const int bx = nid & 7;
    const int path = (nid >> 3) & 1;
    const int bz = nid >> 4;
    const int r0 = bx * 128;

    const u16* W1p = path ? sw1p : cw1p;
    const float* B1 = path ? sb1 : cb1;
    const u16* W2p = path ? sw2p : cw2p;
    const float* B2 = path ? sb2 : cb2;
    u16* O2 = path ? pT : fT;
    const int S2 = path ? M_DIM : L_DIM;

    const u16* Ap = xP + (size_t)bz * N_LOC * C_IN + (size_t)bx * (128 * C_IN);

    f32x4 acc1[4][8];
#pragma unroll
    for (int mi = 0; mi < 4; ++mi)
#pragma unroll
        for (int ni = 0; ni < 8; ++ni)
            acc1[mi][ni] = (f32x4){0.f, 0.f, 0.f, 0.f};

    const int nk = C_IN / 64;   // 12

#define STG_A(db_, kt_)                                                        \
    do {                                                                       \
        _Pragma("unroll")                                                      \
        for (int j_ = 0; j_ < 2; ++j_)                                         \
            load_lds16(Ap + (size_t)(kt_) * 8192 + (size_t)(j_ * 512 + tid) * 8, \
                       &LDSu[(db_) * 8192 + (j_ * 512 + tid) * 8]);            \
    } while (0)
#define STG_B(db_, kt_)                                                        \
    do {                                                                       \
        _Pragma("unroll")                                                      \
        for (int j_ = 0; j_ < 8; ++j_)                                         \
            load_lds16(W1p + (size_t)(kt_) * 32768 + (size_t)(j_ * 512 + tid) * 8, \
                       &LDSu[16384 + (db_) * 32768 + (j_ * 512 + tid) * 8]);   \
    } while (0)

#define AV_PTR(db_, kk_, mi_)                                                  \
    ((const bf16x8*)&LDSu[(db_) * 8192 + ((kk_) * 4 + (lane >> 4)) * 1024 +    \
                          (64 * wr + 16 * (mi_) + (lane & 15)) * 8])
#define BW_PTR(db_, kk_, ni_)                                                  \
    ((const bf16x8*)&LDSu[16384 + (db_) * 32768 +                              \
                          ((kk_) * 4 + (lane >> 4)) * 4096 +                   \
                          (128 * wc + 16 * (ni_) + (lane & 15)) * 8])

#define PHASE_MID()                                                            \
    __builtin_amdgcn_s_barrier();                                              \
    asm volatile("s_waitcnt lgkmcnt(0)" ::: "memory");                         \
    __builtin_amdgcn_sched_barrier(0);                                         \
    __builtin_amdgcn_s_setprio(1)

#define PHASE_END()                                                            \
    __builtin_amdgcn_s_setprio(0);                                             \
    __builtin_amdgcn_sched_barrier(0);                                         \
    __builtin_amdgcn_s_barrier()

    // prologue: tile0 staged, drained.
    STG_A(0, 0);
    STG_B(0, 0);
    asm volatile("s_waitcnt vmcnt(0)" ::: "memory");
    __builtin_amdgcn_s_barrier();

    for (int t = 0; t < nk; ++t) {
        const int db = t & 1;
        bf16x8 av[4], bw[8];

        // ---- phase 0 : kk = 0 (K 0..31 of the tile)
#pragma unroll
        for (int mi = 0; mi < 4; ++mi) av[mi] = *AV_PTR(db, 0, mi);
#pragma unroll
        for (int ni = 0; ni < 8; ++ni) bw[ni] = *BW_PTR(db, 0, ni);
        if (t + 1 < nk) {
            STG_B(db ^ 1, t + 1);
            STG_A(db ^ 1, t + 1);
        }
        PHASE_MID();
#pragma unroll
        for (int mi = 0; mi < 4; ++mi)
#pragma unroll
            for (int ni = 0; ni < 8; ++ni)
                acc1[mi][ni] = __builtin_amdgcn_mfma_f32_16x16x32_bf16(
                    av[mi], bw[ni], acc1[mi][ni], 0, 0, 0);
        PHASE_END();

        // ---- phase 1 : kk = 1 (K 32..63)
#pragma unroll
        for (int mi = 0; mi < 4; ++mi) av[mi] = *AV_PTR(db, 1, mi);
#pragma unroll
        for (int ni = 0; ni < 8; ++ni) bw[ni] = *BW_PTR(db, 1, ni);
        PHASE_MID();
#pragma unroll
        for (int mi = 0; mi < 4; ++mi)
#pragma unroll
            for (int ni = 0; ni < 8; ++ni)
                acc1[mi][ni] = __builtin_amdgcn_mfma_f32_16x16x32_bf16(
                    av[mi], bw[ni], acc1[mi][ni], 0, 0, 0);
        __builtin_amdgcn_s_setprio(0);
        __builtin_amdgcn_sched_barrier(0);
        asm volatile("s_waitcnt vmcnt(0)" ::: "memory");   // t+1 landed
        __builtin_amdgcn_s_barrier();
    }
#undef STG_A
#undef STG_B
#undef AV_PTR
#undef BW_PTR
#undef PHASE_MID
#undef PHASE_END

    // ---- handoff: bias+relu, h -> LDS as [64 cchunk][128 n][8] bf16
    {
        float bv1[8];
#pragma unroll
        for (int ni = 0; ni < 8; ++ni)
            bv1[ni] = B1[128 * wc + 16 * ni + (lane & 15)];
#pragma unroll
        for (int mi = 0; mi < 4; ++mi)
#pragma unroll
            for (int ni = 0; ni < 8; ++ni)
#pragma unroll
                for (int rr = 0; rr < 4; ++rr) {
                    int n = 64 * wr + 16 * mi + (lane >> 4) * 4 + rr;
                    int c = 128 * wc + 16 * ni + (lane & 15);
                    float v = fmaxf(acc1[mi][ni][rr] + bv1[ni], 0.f);
                    LDSu[(c >> 3) * 1024 + n * 8 + (c & 7)] = f2bf(v);
                }
    }
    __syncthreads();

    // ---- stage-2: Out2 = h . W2^T + b2, K=512 in 16 chunks of 32.
    f32x4 acc2[4][2];
#pragma unroll
    for (int mi = 0; mi < 4; ++mi) {
        acc2[mi][0] = (f32x4){0.f, 0.f, 0.f, 0.f};
        acc2[mi][1] = (f32x4){0.f, 0.f, 0.f, 0.f};
    }
    const int c2base = (S2 == L_DIM) ? 32 * wc : 16 * wc;
    const int cA = c2base + (lane & 15);
    const int cB = c2base + 16 + (lane & 15);   // f-path only
    const int fb0 = (lane >> 4) * S2 + cA;      // packed fragment index
    const int fb1 = (lane >> 4) * S2 + cB;

    bf16x8 w0n = *(const bf16x8*)(W2p + (size_t)fb0 * 8);
    bf16x8 w1n = {};
    if (S2 == L_DIM) w1n = *(const bf16x8*)(W2p + (size_t)fb1 * 8);

    for (int k2 = 0; k2 < 16; ++k2) {
        bf16x8 w0 = w0n, w1 = w1n;
        if (k2 < 15) {
            w0n = *(const bf16x8*)(W2p + ((size_t)(k2 + 1) * 4 * S2 + fb0) * 8);
            if (S2 == L_DIM)
                w1n = *(const bf16x8*)(W2p + ((size_t)(k2 + 1) * 4 * S2 + fb1) * 8);
        }
        bf16x8 a2[4];
#pragma unroll
        for (int mi = 0; mi < 4; ++mi)
            a2[mi] = *(const bf16x8*)&LDSu[(k2 * 4 + (lane >> 4)) * 1024 +
                                           (64 * wr + 16 * mi + (lane & 15)) * 8];
#pragma unroll
        for (int mi = 0; mi < 4; ++mi) {
            acc2[mi][0] = __builtin_amdgcn_mfma_f32_16x16x32_bf16(
                a2[mi], w0, acc2[mi][0], 0, 0, 0);
            if (S2 == L_DIM)
                acc2[mi][1] = __builtin_amdgcn_mfma_f32_16x16x32_bf16(
                    a2[mi], w1, acc2[mi][1], 0, 0, 0);
        }
    }

    const float b20 = B2[cA];
    const float b21 = (S2 == L_DIM) ? B2[cB] : 0.f;
    u16* Ob = O2 + (size_t)bz * N_LOC * S2;
#pragma unroll
    for (int mi = 0; mi < 4; ++mi)
#pragma unroll
        for (int rr = 0; rr < 4; ++rr) {
            int row = r0 + 64 * wr + 16 * mi + (lane >> 4) * 4 + rr;
            Ob[(size_t)row * S2 + cA] = f2bf(acc2[mi][0][rr] + b20);
            if (S2 == L_DIM)
                Ob[(size_t)row * S2 + cB] = f2bf(acc2[mi][1][rr] + b21);
        }
}

// ---------------------------------------------------------------------------
// Token MLP stage 1: hidb[b][j] = relu(t[b] . tw1[j] + tb1[j]); grid (8,B).
// ---------------------------------------------------------------------------
__global__ __launch_bounds__(256) void tok1_kernel(const float* __restrict__ t,
                                                   const float* __restrict__ tw1,
                                                   const float* __restrict__ tb1,
                                                   float* __restrict__ hidb) {
    __shared__ __align__(16) float tl[C_IN];
    const int b = blockIdx.y;
    const int j0 = blockIdx.x * 64;
    const int tid = threadIdx.x;
    const int lane = tid & 63;
    const int wave = tid >> 6;
    for (int i = tid; i < C_IN; i += 256) tl[i] = t[(size_t)b * C_IN + i];
    __syncthreads();
    for (int j = wave; j < 64; j += 4) {
        const int row = j0 + j;
        const float4* wr = (const float4*)(tw1 + (size_t)row * C_IN);
        const float4* tr = (const float4*)tl;
        float s = 0.f;
#pragma unroll
        for (int q = 0; q < 3; ++q) {
            float4 wv = wr[lane + 64 * q];
            float4 tv = tr[lane + 64 * q];
            s += wv.x * tv.x + wv.y * tv.y + wv.z * tv.z + wv.w * tv.w;
        }
        s = waveReduceSum(s);
        if (lane == 0) hidb[(size_t)b * HID + row] = fmaxf(s + tb1[row], 0.f);
    }
}

// ---------------------------------------------------------------------------
// Token MLP stage 2: tok[b][g] = hidb[b] . tw2[g] + tb2[g]; grid (4,B).
// ---------------------------------------------------------------------------
__global__ __launch_bounds__(256) void tok2_kernel(const float* __restrict__ hidb,
                                                   const float* __restrict__ tw2,
                                                   const float* __restrict__ tb2,
                                                   float* __restrict__ tok) {
    __shared__ __align__(16) float hl[HID];
    const int b = blockIdx.y;
    const int g0 = blockIdx.x * 64;
    const int tid = threadIdx.x;
    const int lane = tid & 63;
    const int wave = tid >> 6;
    for (int i = tid; i < HID; i += 256) hl[i] = hidb[(size_t)b * HID + i];
    __syncthreads();
    for (int j = wave; j < 64; j += 4) {
        const int row = g0 + j;
        const float4* wr = (const float4*)(tw2 + (size_t)row * HID);
        const float4* hr = (const float4*)hl;
        float s = 0.f;
#pragma unroll
        for (int q = 0; q < 2; ++q) {
            float4 wv = wr[lane + 64 * q];
            float4 hv = hr[lane + 64 * q];
            s += wv.x * hv.x + wv.y * hv.y + wv.z * hv.z + wv.w * hv.w;
        }
        s = waveReduceSum(s);
        if (lane == 0) tok[(size_t)b * G_DIM + row] = s + tb2[row];
    }
}

// ---------------------------------------------------------------------------
// Sinkhorn, linear domain (round-9, verified): E = exp(p) cached bf16;
// eu/ev iterations are pure mul-add; P = E*eu*ev*1088.
// ---------------------------------------------------------------------------
__global__ __launch_bounds__(1024) void sinkhorn_kernel(const u16* __restrict__ pT,
                                                        const float* __restrict__ dust,
                                                        float* __restrict__ PT) {
    __shared__ u16 sp[M_DIM][N_LOC];   // holds E = exp(p), bf16
    __shared__ float eu[M_DIM + 1];
    __shared__ float ev[N_LOC];
    const int b = blockIdx.x;
    const int t = threadIdx.x;
    const int lane = t & 63;
    const int wave = t >> 6;
    const float alpha = dust[0];
    const float Ea = __expf(alpha);
    const float mu = 1.f / 1088.f;
    const float mu64 = 960.f / 1088.f;
    const float nu = 1.f / 1088.f;

    const uint4* prow = (const uint4*)(pT + ((size_t)b * N_LOC + t) * M_DIM);
#pragma unroll
    for (int q = 0; q < 8; ++q) {
        uint4 ch = prow[q];
        sp[q * 8 + 0][t] = (u16)(ch.x);
        sp[q * 8 + 1][t] = (u16)(ch.x >> 16);
        sp[q * 8 + 2][t] = (u16)(ch.y);
        sp[q * 8 + 3][t] = (u16)(ch.y >> 16);
        sp[q * 8 + 4][t] = (u16)(ch.z);
        sp[q * 8 + 5][t] = (u16)(ch.z >> 16);
        sp[q * 8 + 6][t] = (u16)(ch.w);
        sp[q * 8 + 7][t] = (u16)(ch.w >> 16);
    }
#pragma unroll
    for (int m = 0; m < M_DIM; ++m)
        sp[m][t] = f2bf(__expf(bf2f(sp[m][t])));
    ev[t] = 1.f;
    __syncthreads();

    for (int it = 0; it < 3; ++it) {
        for (int m = wave; m < M_DIM + 1; m += 16) {
            float s = 0.f;
            if (m < M_DIM) {
#pragma unroll
                for (int q = 0; q < 16; ++q) {
                    int c = lane + 64 * q;
                    s += bf2f(sp[m][c]) * ev[c];
                }
            } else {
#pragma unroll
                for (int q = 0; q < 16; ++q) {
                    int c = lane + 64 * q;
                    s += ev[c];
                }
                s *= Ea;
            }
            s = waveReduceSum(s);
            if (lane == 0) eu[m] = ((m < M_DIM) ? mu : mu64) / s;
        }
        __syncthreads();
        float s = Ea * eu[M_DIM];
#pragma unroll 8
        for (int m = 0; m < M_DIM; ++m) s += bf2f(sp[m][t]) * eu[m];
        ev[t] = nu / s;
        __syncthreads();
    }

    const float evt = ev[t] * 1088.f;
    float* Prow = PT + ((size_t)b * N_LOC + t) * M_DIM;
#pragma unroll
    for (int m4 = 0; m4 < M_DIM; m4 += 4) {
        float4 o;
        o.x = bf2f(sp[m4 + 0][t]) * eu[m4 + 0] * evt;
        o.y = bf2f(sp[m4 + 1][t]) * eu[m4 + 1] * evt;
        o.z = bf2f(sp[m4 + 2][t]) * eu[m4 + 2] * evt;
        o.w = bf2f(sp[m4 + 3][t]) * eu[m4 + 3] * evt;
        *(float4*)(Prow + m4) = o;
    }
}

// ---------------------------------------------------------------------------
// agg[b,l,m] = sum_n fT[b,n,l] * PT[b,n,m]. grid (4,B), 256 thr (round-8).
// ---------------------------------------------------------------------------
__global__ __launch_bounds__(256) void agg_kernel(const u16* __restrict__ fT,
                                                  const float* __restrict__ PT,
                                                  float* __restrict__ agg) {
    __shared__ float Fs[64][36];
    __shared__ float Ps[64][68];
    const int b = blockIdx.y;
    const int l0 = blockIdx.x * 32;
    const int tid = threadIdx.x;
    const u16* fb = fT + (size_t)b * N_LOC * L_DIM;
    const float* Pb = PT + (size_t)b * N_LOC * M_DIM;

    const int sn = tid >> 2;
    const int flc = (tid & 3) * 8;
    const int pmc = (tid & 3) * 16;
    const int tl = (tid >> 4) * 2;
    const int tm = (tid & 15) * 4;

    float acc[2][4] = {};

    for (int n0 = 0; n0 < N_LOC; n0 += 64) {
        __syncthreads();
        {
            uint4 ld = *(const uint4*)(fb + (size_t)(n0 + sn) * L_DIM + l0 + flc);
            Fs[sn][flc + 0] = bf2f((u16)(ld.x));
            Fs[sn][flc + 1] = bf2f((u16)(ld.x >> 16));
            Fs[sn][flc + 2] = bf2f((u16)(ld.y));
            Fs[sn][flc + 3] = bf2f((u16)(ld.y >> 16));
            Fs[sn][flc + 4] = bf2f((u16)(ld.z));
            Fs[sn][flc + 5] = bf2f((u16)(ld.z >> 16));
            Fs[sn][flc + 6] = bf2f((u16)(ld.w));
            Fs[sn][flc + 7] = bf2f((u16)(ld.w >> 16));
        }
#pragma unroll
        for (int i = 0; i < 4; ++i) {
            float4 vv = *(const float4*)(Pb + (size_t)(n0 + sn) * M_DIM + pmc + 4 * i);
            *(float4*)&Ps[sn][pmc + 4 * i] = vv;
        }
        __syncthreads();
#pragma unroll 8
        for (int nn = 0; nn < 64; ++nn) {
            float a0 = Fs[nn][tl];
            float a1 = Fs[nn][tl + 1];
            float4 p4 = *(const float4*)&Ps[nn][tm];
            acc[0][0] = fmaf(a0, p4.x, acc[0][0]);
            acc[0][1] = fmaf(a0, p4.y, acc[0][1]);
            acc[0][2] = fmaf(a0, p4.z, acc[0][2]);
            acc[0][3] = fmaf(a0, p4.w, acc[0][3]);
            acc[1][0] = fmaf(a1, p4.x, acc[1][0]);
            acc[1][1] = fmaf(a1, p4.y, acc[1][1]);
            acc[1][2] = fmaf(a1, p4.z, acc[1][2]);
            acc[1][3] = fmaf(a1, p4.w, acc[1][3]);
        }
    }

#pragma unroll
    for (int i = 0; i < 2; ++i) {
        float* dst = agg + ((size_t)b * L_DIM + l0 + tl + i) * M_DIM + tm;
        *(float4*)dst = make_float4(acc[i][0], acc[i][1], acc[i][2], acc[i][3]);
    }
}

// ---------------------------------------------------------------------------
// Final normalization cascade (round-8). grid B, 256 thr.
// ---------------------------------------------------------------------------
__global__ __launch_bounds__(256) void final_kernel(const float* __restrict__ agg,
                                                    const float* __restrict__ tok,
                                                    float* __restrict__ out) {
    __shared__ __align__(16) float ag[L_DIM * M_DIM];
    __shared__ float rm[M_DIM];
    __shared__ float red[4];
    __shared__ float tk[G_DIM];
    const int b = blockIdx.x;
    const int tid = threadIdx.x;
    const int lane = tid & 63;
    const int wave = tid >> 6;
    const float EPS = 1e-12f;

    const float4* ab = (const float4*)(agg + (size_t)b * L_DIM * M_DIM);
    for (int e4 = tid; e4 < L_DIM * M_DIM / 4; e4 += 256) ((float4*)ag)[e4] = ab[e4];
    tk[tid] = tok[(size_t)b * G_DIM + tid];
    __syncthreads();

    if (tid < M_DIM) {
        float ss = 0.f;
#pragma unroll 8
        for (int l = 0; l < L_DIM; ++l) {
            float x = ag[l * M_DIM + tid];
            ss = fmaf(x, x, ss);
        }
        rm[tid] = 1.f / fmaxf(sqrtf(ss), EPS);
    }
    const float tv = tk[tid];
    float ssl = tv * tv;
    ssl = waveReduceSum(ssl);
    if (lane == 0) red[wave] = ssl;
    __syncthreads();
    const float stok = red[0] + red[1] + red[2] + red[3];
    const float rt = 1.f / fmaxf(sqrtf(stok), EPS);
    const float tn = tv * rt;

    float gs = tn * tn;
    for (int e = tid; e < L_DIM * M_DIM; e += 256) {
        float x = ag[e] * rm[e & (M_DIM - 1)];
        gs = fmaf(x, x, gs);
    }
    __syncthreads();
    gs = waveReduceSum(gs);
    if (lane == 0) red[wave] = gs;
    __syncthreads();
    const float G = red[0] + red[1] + red[2] + red[3];
    const float rg = 1.f / fmaxf(sqrtf(G), EPS);

    float* ob = out + (size_t)b * (G_DIM + L_DIM * M_DIM);
    ob[tid] = tn * rg;
    for (int e = tid; e < L_DIM * M_DIM; e += 256)
        ob[G_DIM + e] = ag[e] * rm[e & (M_DIM - 1)] * rg;
}

// ---------------------------------------------------------------------------
extern "C" void kernel_launch(void* const* d_in, const int* in_sizes, int n_in,
                              void* d_out, int out_size, void* d_ws, size_t ws_size,
                              hipStream_t stream) {
    const float* x    = (const float*)d_in[0];
    const float* t    = (const float*)d_in[1];
    const float* tw1  = (const float*)d_in[2];
    const float* tb1  = (const float*)d_in[3];
    const float* tw2  = (const float*)d_in[4];
    const float* tb2  = (const float*)d_in[5];
    const float* cw1  = (const float*)d_in[6];
    const float* cb1  = (const float*)d_in[7];
    const float* cw2  = (const float*)d_in[8];
    const float* cb2  = (const float*)d_in[9];
    const float* sw1  = (const float*)d_in[10];
    const float* sb1  = (const float*)d_in[11];
    const float* sw2  = (const float*)d_in[12];
    const float* sb2  = (const float*)d_in[13];
    const float* dust = (const float*)d_in[14];
    float* out = (float*)d_out;

    char* ws = (char*)d_ws;
    u16* xP    = (u16*)(ws);                         // 100,663,296
    u16* fT    = (u16*)(ws + 100663296ull);          //  16,777,216
    u16* pT    = (u16*)(ws + 117440512ull);          //   8,388,608
    u16* cw1p  = (u16*)(ws + 125829120ull);          //     786,432
    u16* sw1p  = (u16*)(ws + 126615552ull);          //     786,432
    u16* cw2p  = (u16*)(ws + 127401984ull);          //     131,072
    u16* sw2p  = (u16*)(ws + 127533056ull);          //      65,536
    float* hidb = (float*)(ws + 127598592ull);       //     131,072
    // reuse of dead xP region after fused12:
    float* PT     = (float*)(ws);                    //  16,777,216
    float* tokbuf = (float*)(ws + 20971520ull);      //      65,536
    float* aggbuf = (float*)(ws + 25165824ull);      //   2,097,152

    prep_weights<<<432, 256, 0, stream>>>(cw1, sw1, cw2, sw2,
                                          cw1p, sw1p, cw2p, sw2p);
    transpose_x<<<dim3(N_LOC / 64, C_IN / 64, B_SZ), 256, 0, stream>>>(x, xP);

    fused12<<<dim3(8, 2, B_SZ), 512, 0, stream>>>(
        xP, cw1p, cb1, cw2p, cb2, sw1p, sb1, sw2p, sb2, fT, pT);

    tok1_kernel<<<dim3(HID / 64, B_SZ), 256, 0, stream>>>(t, tw1, tb1, hidb);
    tok2_kernel<<<dim3(G_DIM / 64, B_SZ), 256, 0, stream>>>(hidb, tw2, tb2, tokbuf);

    sinkhorn_kernel<<<B_SZ, 1024, 0, stream>>>(pT, dust, PT);
    agg_kernel<<<dim3(L_DIM / 32, B_SZ), 256, 0, stream>>>(fT, PT, aggbuf);
    final_kernel<<<B_SZ, 256, 0, stream>>>(aggbuf, tokbuf, out);
}

// Round 11
// 275.379 us; speedup vs baseline: 1.1164x; 1.0584x over previous
//
#include <hip/hip_runtime.h>
#include <math.h>

// ---------------------------------------------------------------------------
// SALAD forward, round 11:
//  - fused12: BK=32, ONE barrier-pair per K-tile (24 pairs vs 48), counted
//    vmcnt(1) window restored (T4). Order per tile:
//    {reads; STG_B(t+1); lgkm(0); barrier; STG_A(t+2); 32 MFMA; vmcnt(1); barrier}
//  - PT (Sinkhorn output / agg input) in bf16: halves that traffic.
//  - linear-domain sinkhorn, split agg/final, packed staging all kept.
// B=64, C=768, N=1024, HID=512, L=128, M=64, G=256.
// ---------------------------------------------------------------------------

#define B_SZ   64
#define C_IN   768
#define N_LOC  1024
#define HID    512
#define L_DIM  128
#define M_DIM  64
#define G_DIM  256

typedef unsigned short u16;
typedef __bf16 bf16x8 __attribute__((ext_vector_type(8)));
typedef float f32x4 __attribute__((ext_vector_type(4)));

typedef const __attribute__((address_space(1))) void* gptr_t;
typedef __attribute__((address_space(3))) void* sptr_t;

__device__ __forceinline__ void load_lds16(const void* g, void* l) {
    __builtin_amdgcn_global_load_lds((gptr_t)g, (sptr_t)l, 16, 0, 0);
}

__device__ __forceinline__ u16 f2bf(float f) {  // round-to-nearest-even
    unsigned u = __float_as_uint(f);
    u += 0x7fffu + ((u >> 16) & 1u);
    return (u16)(u >> 16);
}
__device__ __forceinline__ float bf2f(u16 h) {
    return __uint_as_float(((unsigned)h) << 16);
}

__device__ __forceinline__ float waveReduceSum(float v) {
#pragma unroll
    for (int off = 32; off > 0; off >>= 1) v += __shfl_xor(v, off, 64);
    return v;
}

// ---------------------------------------------------------------------------
// Weight prep (one launch; packs W1 -> [kchunk][c][8], W2 -> [k2][kc][c][8]).
// ---------------------------------------------------------------------------
__global__ __launch_bounds__(256) void prep_weights(
        const float* __restrict__ cw1, const float* __restrict__ sw1,
        const float* __restrict__ cw2, const float* __restrict__ sw2,
        u16* __restrict__ cw1p, u16* __restrict__ sw1p,
        u16* __restrict__ cw2p, u16* __restrict__ sw2p) {
    const int q = blockIdx.x * 256 + threadIdx.x;
    const float* src;
    u16* dst;
    if (q < 98304) {                       // W1: 2 x 96 kchunk x 512 c
        int path = q / 49152, r = q % 49152;
        int kch = r / 512, c = r & 511;
        src = (path ? sw1 : cw1) + (size_t)c * C_IN + kch * 8;
        dst = (path ? sw1p : cw1p) + (size_t)r * 8;
    } else {                               // W2: f 8192 + p 4096 chunks
        int q2 = q - 98304;
        int path = (q2 >= 8192) ? 1 : 0;
        int r = q2 - (path ? 8192 : 0);
        int S2 = path ? M_DIM : L_DIM;
        int k2 = r / (4 * S2), kc = (r / S2) & 3, c = r % S2;
        src = (path ? sw2 : cw2) + (size_t)c * HID + k2 * 32 + kc * 8;
        dst = (path ? sw2p : cw2p) + (size_t)r * 8;
    }
    float4 v0 = *(const float4*)(src);
    float4 v1 = *(const float4*)(src + 4);
    *(ushort4*)(dst) = make_ushort4(f2bf(v0.x), f2bf(v0.y), f2bf(v0.z), f2bf(v0.w));
    *(ushort4*)(dst + 4) = make_ushort4(f2bf(v1.x), f2bf(v1.y), f2bf(v1.z), f2bf(v1.w));
}

// ---------------------------------------------------------------------------
// x [B][C][N] fp32 -> xPack bf16 in A-tile LDS image order:
//   off(b,n,c) = b*N*C + (n>>7)*(128*C) + (c>>3)*1024 + (n&127)*8 + (c&7)
// grid = (N/64, C/64, B), block 256.
// ---------------------------------------------------------------------------
__global__ __launch_bounds__(256) void transpose_x(const float* __restrict__ x,
                                                   u16* __restrict__ xP) {
    __shared__ float tile[64][65];
    const int n0 = blockIdx.x * 64;
    const int c0 = blockIdx.y * 64;
    const size_t b = blockIdx.z;
    const float* xb = x + b * (size_t)(C_IN * N_LOC);
    u16* xpb = xP + b * (size_t)(N_LOC * C_IN);
    const int tid = threadIdx.x;

    const int jn = (tid & 15) * 4;
    const int cr = tid >> 4;
#pragma unroll
    for (int r = 0; r < 4; ++r) {
        int c = cr + r * 16;
        float4 v = *(const float4*)(xb + (size_t)(c0 + c) * N_LOC + n0 + jn);
        tile[c][jn + 0] = v.x;
        tile[c][jn + 1] = v.y;
        tile[c][jn + 2] = v.z;
        tile[c][jn + 3] = v.w;
    }
    __syncthreads();

    const int n = tid & 63;
    const int ch0 = tid >> 6;        // 0..3
    const int nG = n0 + n;
#pragma unroll
    for (int r = 0; r < 2; ++r) {
        const int ch = ch0 + r * 4;          // 0..7
        const int cG = c0 + ch * 8;
        u16* dst = xpb + (size_t)(nG >> 7) * (128 * C_IN) + (cG >> 3) * 1024 +
                   (nG & 127) * 8;
        ushort4 o0 = make_ushort4(f2bf(tile[ch * 8 + 0][n]), f2bf(tile[ch * 8 + 1][n]),
                                  f2bf(tile[ch * 8 + 2][n]), f2bf(tile[ch * 8 + 3][n]));
        ushort4 o1 = make_ushort4(f2bf(tile[ch * 8 + 4][n]), f2bf(tile[ch * 8 + 5][n]),
                                  f2bf(tile[ch * 8 + 6][n]), f2bf(tile[ch * 8 + 7][n]));
        *(ushort4*)(dst) = o0;
        *(ushort4*)(dst + 4) = o1;
    }
}

// ---------------------------------------------------------------------------
// Fused stage-1 + stage-2, BK=32, one barrier-pair per tile, counted vmcnt.
// Stage-1: h[128 n][512 c] = relu(x . W1^T + b1), nk=24 K-tiles.
//   8 waves (2 row-halves x 4 col-quarters), acc1[4][8], 32 MFMA/tile/wave.
//   LDS (128 KiB union): A[2][4096 u16] at 0 ([kc4][n128][8]);
//                        B[2][16384 u16] at 8192 ([kc4][c512][8]).
//   tile t (buf db=t&1):
//     12 ds_reads (av[4], bw[8]) | STG_B(t+1)->db^1
//     lgkmcnt(0); barrier                (all waves' reads of tile t retired)
//     STG_A(t+2)->db                     (safe: av reads retired block-wide)
//     setprio(1); 32 MFMA; setprio(0)
//     vmcnt(1); barrier                  (B(t+1)+A(t+1) landed; A(t+2) in flight)
// Handoff: h -> LDS [64 cchunk][128 n][8]; then stage-2 as before.
// grid (8, 2, 64) XCD-bijective remap; 512 threads.
// ---------------------------------------------------------------------------
__global__ __launch_bounds__(512, 2) void fused12(
        const u16* __restrict__ xP,
        const u16* __restrict__ cw1p, const float* __restrict__ cb1,
        const u16* __restrict__ cw2p, const float* __restrict__ cb2,
        const u16* __restrict__ sw1p, const float* __restrict__ sb1,
        const u16* __restrict__ sw2p, const float* __restrict__ sb2,
        u16* __restrict__ fT, u16* __restrict__ pT) {
    __shared__ __align__(16) u16 LDSu[65536];   // 128 KiB union
    const int tid = threadIdx.x;
    const int lane = tid & 63;
    const int wid = tid >> 6;
    const int wr = wid >> 2;   // 0..1 : row half (64 rows)
    const int wc = wid & 3;    // 0..3 : col quarter (128 cols)

    const int id = blockIdx.x + 8 * blockIdx.y + 16 * blockIdx.z;
    const int nid = (id & 7) * 128 + (id >> 3);   // 1024 % 8 == 0, bijective
    const int bx = nid & 7;
    const int path = (nid >> 3) & 1;
    const int bz = nid >> 4;
    const int r0 = bx * 128;

    const u16* W1p = path ? sw1p : cw1p;
    const float* B1 = path ? sb1 : cb1;
    const u16* W2p = path ? sw2p : cw2p;
    const float* B2 = path ? sb2 : cb2;
    u16* O2 = path ? pT : fT;
    const int S2 = path ? M_DIM : L_DIM;

    const u16* Ap = xP + (size_t)bz * N_LOC * C_IN + (size_t)bx * (128 * C_IN);

    f32x4 acc1[4][8];
#pragma unroll
    for (int mi = 0; mi < 4; ++mi)
#pragma unroll
        for (int ni = 0; ni < 8; ++ni)
            acc1[mi][ni] = (f32x4){0.f, 0.f, 0.f, 0.f};

    const int nk = C_IN / 32;   // 24

#define STG_A(db_, kt_)                                                        \
    load_lds16(Ap + (size_t)(kt_) * 4096 + tid * 8, &LDSu[(db_) * 4096 + tid * 8])
#define STG_B(db_, kt_)                                                        \
    do {                                                                       \
        _Pragma("unroll")                                                      \
        for (int j_ = 0; j_ < 4; ++j_)                                         \
            load_lds16(W1p + (size_t)(kt_) * 16384 + (size_t)(j_ * 512 + tid) * 8, \
                       &LDSu[8192 + (db_) * 16384 + (j_ * 512 + tid) * 8]);    \
    } while (0)

#define AV_PTR(db_, mi_)                                                       \
    ((const bf16x8*)&LDSu[(db_) * 4096 + (lane >> 4) * 1024 +                  \
                          (64 * wr + 16 * (mi_) + (lane & 15)) * 8])
#define BW_PTR(db_, ni_)                                                       \
    ((const bf16x8*)&LDSu[8192 + (db_) * 16384 + (lane >> 4) * 4096 +          \
                          (128 * wc + 16 * (ni_) + (lane & 15)) * 8])

    // prologue: A(0),B(0),A(1). vmcnt(1): tile0 landed, A(1) in flight.
    STG_A(0, 0);
    STG_B(0, 0);
    STG_A(1, 1);
    asm volatile("s_waitcnt vmcnt(1)" ::: "memory");
    __builtin_amdgcn_s_barrier();

    for (int t = 0; t < nk; ++t) {
        const int db = t & 1;
        bf16x8 av[4], bw[8];

#pragma unroll
        for (int mi = 0; mi < 4; ++mi) av[mi] = *AV_PTR(db, mi);
#pragma unroll
        for (int ni = 0; ni < 8; ++ni) bw[ni] = *BW_PTR(db, ni);
        if (t + 1 < nk) STG_B(db ^ 1, t + 1);

        asm volatile("s_waitcnt lgkmcnt(0)" ::: "memory");
        __builtin_amdgcn_sched_barrier(0);
        __builtin_amdgcn_s_barrier();          // all waves' reads(t) retired

        if (t + 2 < nk) STG_A(db, t + 2);      // safe: av reads retired block-wide

        __builtin_amdgcn_s_setprio(1);
#pragma unroll
        for (int mi = 0; mi < 4; ++mi)
#pragma unroll
            for (int ni = 0; ni < 8; ++ni)
                acc1[mi][ni] = __builtin_amdgcn_mfma_f32_16x16x32_bf16(
                    av[mi], bw[ni], acc1[mi][ni], 0, 0, 0);
        __builtin_amdgcn_s_setprio(0);
        __builtin_amdgcn_sched_barrier(0);

        if (t + 2 < nk)
            asm volatile("s_waitcnt vmcnt(1)" ::: "memory");
        else
            asm volatile("s_waitcnt vmcnt(0)" ::: "memory");
        __builtin_amdgcn_s_barrier();          // tile t+1 fully visible
    }
#undef STG_A
#undef STG_B
#undef AV_PTR
#undef BW_PTR

    // ---- handoff: bias+relu, h -> LDS as [64 cchunk][128 n][8] bf16
    {
        float bv1[8];
#pragma unroll
        for (int ni = 0; ni < 8; ++ni)
            bv1[ni] = B1[128 * wc + 16 * ni + (lane & 15)];
#pragma unroll
        for (int mi = 0; mi < 4; ++mi)
#pragma unroll
            for (int ni = 0; ni < 8; ++ni)
#pragma unroll
                for (int rr = 0; rr < 4; ++rr) {
                    int n = 64 * wr + 16 * mi + (lane >> 4) * 4 + rr;
                    int c = 128 * wc + 16 * ni + (lane & 15);
                    float v = fmaxf(acc1[mi][ni][rr] + bv1[ni], 0.f);
                    LDSu[(c >> 3) * 1024 + n * 8 + (c & 7)] = f2bf(v);
                }
    }
    __syncthreads();

    // ---- stage-2: Out2 = h . W2^T + b2, K=512 in 16 chunks of 32.
    f32x4 acc2[4][2];
#pragma unroll
    for (int mi = 0; mi < 4; ++mi) {
        acc2[mi][0] = (f32x4){0.f, 0.f, 0.f, 0.f};
        acc2[mi][1] = (f32x4){0.f, 0.f, 0.f, 0.f};
    }
    const int c2base = (S2 == L_DIM) ? 32 * wc : 16 * wc;
    const int cA = c2base + (lane & 15);
    const int cB = c2base + 16 + (lane & 15);   // f-path only
    const int fb0 = (lane >> 4) * S2 + cA;      // packed fragment index
    const int fb1 = (lane >> 4) * S2 + cB;

    bf16x8 w0n = *(const bf16x8*)(W2p + (size_t)fb0 * 8);
    bf16x8 w1n = {};
    if (S2 == L_DIM) w1n = *(const bf16x8*)(W2p + (size_t)fb1 * 8);

    for (int k2 = 0; k2 < 16; ++k2) {
        bf16x8 w0 = w0n, w1 = w1n;
        if (k2 < 15) {
            w0n = *(const bf16x8*)(W2p + ((size_t)(k2 + 1) * 4 * S2 + fb0) * 8);
            if (S2 == L_DIM)
                w1n = *(const bf16x8*)(W2p + ((size_t)(k2 + 1) * 4 * S2 + fb1) * 8);
        }
        bf16x8 a2[4];
#pragma unroll
        for (int mi = 0; mi < 4; ++mi)
            a2[mi] = *(const bf16x8*)&LDSu[(k2 * 4 + (lane >> 4)) * 1024 +
                                           (64 * wr + 16 * mi + (lane & 15)) * 8];
#pragma unroll
        for (int mi = 0; mi < 4; ++mi) {
            acc2[mi][0] = __builtin_amdgcn_mfma_f32_16x16x32_bf16(
                a2[mi], w0, acc2[mi][0], 0, 0, 0);
            if (S2 == L_DIM)
                acc2[mi][1] = __builtin_amdgcn_mfma_f32_16x16x32_bf16(
                    a2[mi], w1, acc2[mi][1], 0, 0, 0);
        }
    }

    const float b20 = B2[cA];
    const float b21 = (S2 == L_DIM) ? B2[cB] : 0.f;
    u16* Ob = O2 + (size_t)bz * N_LOC * S2;
#pragma unroll
    for (int mi = 0; mi < 4; ++mi)
#pragma unroll
        for (int rr = 0; rr < 4; ++rr) {
            int row = r0 + 64 * wr + 16 * mi + (lane >> 4) * 4 + rr;
            Ob[(size_t)row * S2 + cA] = f2bf(acc2[mi][0][rr] + b20);
            if (S2 == L_DIM)
                Ob[(size_t)row * S2 + cB] = f2bf(acc2[mi][1][rr] + b21);
        }
}

// ---------------------------------------------------------------------------
// Token MLP stage 1: hidb[b][j] = relu(t[b] . tw1[j] + tb1[j]); grid (8,B).
// ---------------------------------------------------------------------------
__global__ __launch_bounds__(256) void tok1_kernel(const float* __restrict__ t,
                                                   const float* __restrict__ tw1,
                                                   const float* __restrict__ tb1,
                                                   float* __restrict__ hidb) {
    __shared__ __align__(16) float tl[C_IN];
    const int b = blockIdx.y;
    const int j0 = blockIdx.x * 64;
    const int tid = threadIdx.x;
    const int lane = tid & 63;
    const int wave = tid >> 6;
    for (int i = tid; i < C_IN; i += 256) tl[i] = t[(size_t)b * C_IN + i];
    __syncthreads();
    for (int j = wave; j < 64; j += 4) {
        const int row = j0 + j;
        const float4* wr = (const float4*)(tw1 + (size_t)row * C_IN);
        const float4* tr = (const float4*)tl;
        float s = 0.f;
#pragma unroll
        for (int q = 0; q < 3; ++q) {
            float4 wv = wr[lane + 64 * q];
            float4 tv = tr[lane + 64 * q];
            s += wv.x * tv.x + wv.y * tv.y + wv.z * tv.z + wv.w * tv.w;
        }
        s = waveReduceSum(s);
        if (lane == 0) hidb[(size_t)b * HID + row] = fmaxf(s + tb1[row], 0.f);
    }
}

// ---------------------------------------------------------------------------
// Token MLP stage 2: tok[b][g] = hidb[b] . tw2[g] + tb2[g]; grid (4,B).
// ---------------------------------------------------------------------------
__global__ __launch_bounds__(256) void tok2_kernel(const float* __restrict__ hidb,
                                                   const float* __restrict__ tw2,
                                                   const float* __restrict__ tb2,
                                                   float* __restrict__ tok) {
    __shared__ __align__(16) float hl[HID];
    const int b = blockIdx.y;
    const int g0 = blockIdx.x * 64;
    const int tid = threadIdx.x;
    const int lane = tid & 63;
    const int wave = tid >> 6;
    for (int i = tid; i < HID; i += 256) hl[i] = hidb[(size_t)b * HID + i];
    __syncthreads();
    for (int j = wave; j < 64; j += 4) {
        const int row = g0 + j;
        const float4* wr = (const float4*)(tw2 + (size_t)row * HID);
        const float4* hr = (const float4*)hl;
        float s = 0.f;
#pragma unroll
        for (int q = 0; q < 2; ++q) {
            float4 wv = wr[lane + 64 * q];
            float4 hv = hr[lane + 64 * q];
            s += wv.x * hv.x + wv.y * hv.y + wv.z * hv.z + wv.w * hv.w;
        }
        s = waveReduceSum(s);
        if (lane == 0) tok[(size_t)b * G_DIM + row] = s + tb2[row];
    }
}

// ---------------------------------------------------------------------------
// Sinkhorn, linear domain: E = exp(p) cached bf16; eu/ev pure mul-add;
// P = E*eu*ev*1088 written as BF16.
// ---------------------------------------------------------------------------
__global__ __launch_bounds__(1024) void sinkhorn_kernel(const u16* __restrict__ pT,
                                                        const float* __restrict__ dust,
                                                        u16* __restrict__ PTb) {
    __shared__ u16 sp[M_DIM][N_LOC];   // holds E = exp(p), bf16
    __shared__ float eu[M_DIM + 1];
    __shared__ float ev[N_LOC];
    const int b = blockIdx.x;
    const int t = threadIdx.x;
    const int lane = t & 63;
    const int wave = t >> 6;
    const float alpha = dust[0];
    const float Ea = __expf(alpha);
    const float mu = 1.f / 1088.f;
    const float mu64 = 960.f / 1088.f;
    const float nu = 1.f / 1088.f;

    const uint4* prow = (const uint4*)(pT + ((size_t)b * N_LOC + t) * M_DIM);
#pragma unroll
    for (int q = 0; q < 8; ++q) {
        uint4 ch = prow[q];
        sp[q * 8 + 0][t] = (u16)(ch.x);
        sp[q * 8 + 1][t] = (u16)(ch.x >> 16);
        sp[q * 8 + 2][t] = (u16)(ch.y);
        sp[q * 8 + 3][t] = (u16)(ch.y >> 16);
        sp[q * 8 + 4][t] = (u16)(ch.z);
        sp[q * 8 + 5][t] = (u16)(ch.z >> 16);
        sp[q * 8 + 6][t] = (u16)(ch.w);
        sp[q * 8 + 7][t] = (u16)(ch.w >> 16);
    }
#pragma unroll
    for (int m = 0; m < M_DIM; ++m)
        sp[m][t] = f2bf(__expf(bf2f(sp[m][t])));
    ev[t] = 1.f;
    __syncthreads();

    for (int it = 0; it < 3; ++it) {
        for (int m = wave; m < M_DIM + 1; m += 16) {
            float s = 0.f;
            if (m < M_DIM) {
#pragma unroll
                for (int q = 0; q < 16; ++q) {
                    int c = lane + 64 * q;
                    s += bf2f(sp[m][c]) * ev[c];
                }
            } else {
#pragma unroll
                for (int q = 0; q < 16; ++q) {
                    int c = lane + 64 * q;
                    s += ev[c];
                }
                s *= Ea;
            }
            s = waveReduceSum(s);
            if (lane == 0) eu[m] = ((m < M_DIM) ? mu : mu64) / s;
        }
        __syncthreads();
        float s = Ea * eu[M_DIM];
#pragma unroll 8
        for (int m = 0; m < M_DIM; ++m) s += bf2f(sp[m][t]) * eu[m];
        ev[t] = nu / s;
        __syncthreads();
    }

    const float evt = ev[t] * 1088.f;
    u16* Prow = PTb + ((size_t)b * N_LOC + t) * M_DIM;
#pragma unroll
    for (int m8 = 0; m8 < M_DIM; m8 += 8) {
        unsigned v0 = f2bf(bf2f(sp[m8 + 0][t]) * eu[m8 + 0] * evt);
        unsigned v1 = f2bf(bf2f(sp[m8 + 1][t]) * eu[m8 + 1] * evt);
        unsigned v2 = f2bf(bf2f(sp[m8 + 2][t]) * eu[m8 + 2] * evt);
        unsigned v3 = f2bf(bf2f(sp[m8 + 3][t]) * eu[m8 + 3] * evt);
        unsigned v4 = f2bf(bf2f(sp[m8 + 4][t]) * eu[m8 + 4] * evt);
        unsigned v5 = f2bf(bf2f(sp[m8 + 5][t]) * eu[m8 + 5] * evt);
        unsigned v6 = f2bf(bf2f(sp[m8 + 6][t]) * eu[m8 + 6] * evt);
        unsigned v7 = f2bf(bf2f(sp[m8 + 7][t]) * eu[m8 + 7] * evt);
        uint4 w;
        w.x = v0 | (v1 << 16);
        w.y = v2 | (v3 << 16);
        w.z = v4 | (v5 << 16);
        w.w = v6 | (v7 << 16);
        *(uint4*)(Prow + m8) = w;
    }
}

// ---------------------------------------------------------------------------
// agg[b,l,m] = sum_n fT[b,n,l] * PTb[b,n,m] (both bf16). grid (4,B), 256 thr.
// ---------------------------------------------------------------------------
__global__ __launch_bounds__(256) void agg_kernel(const u16* __restrict__ fT,
                                                  const u16* __restrict__ PTb,
                                                  float* __restrict__ agg) {
    __shared__ float Fs[64][36];
    __shared__ float Ps[64][68];
    const int b = blockIdx.y;
    const int l0 = blockIdx.x * 32;
    const int tid = threadIdx.x;
    const u16* fb = fT + (size_t)b * N_LOC * L_DIM;
    const u16* Pb = PTb + (size_t)b * N_LOC * M_DIM;

    const int sn = tid >> 2;
    const int flc = (tid & 3) * 8;
    const int pmc = (tid & 3) * 16;
    const int tl = (tid >> 4) * 2;
    const int tm = (tid & 15) * 4;

    float acc[2][4] = {};

    for (int n0 = 0; n0 < N_LOC; n0 += 64) {
        __syncthreads();
        {
            uint4 ld = *(const uint4*)(fb + (size_t)(n0 + sn) * L_DIM + l0 + flc);
            Fs[sn][flc + 0] = bf2f((u16)(ld.x));
            Fs[sn][flc + 1] = bf2f((u16)(ld.x >> 16));
            Fs[sn][flc + 2] = bf2f((u16)(ld.y));
            Fs[sn][flc + 3] = bf2f((u16)(ld.y >> 16));
            Fs[sn][flc + 4] = bf2f((u16)(ld.z));
            Fs[sn][flc + 5] = bf2f((u16)(ld.z >> 16));
            Fs[sn][flc + 6] = bf2f((u16)(ld.w));
            Fs[sn][flc + 7] = bf2f((u16)(ld.w >> 16));
        }
        {
            const u16* psrc = Pb + (size_t)(n0 + sn) * M_DIM + pmc;
            uint4 p0 = *(const uint4*)(psrc);
            uint4 p1 = *(const uint4*)(psrc + 8);
            Ps[sn][pmc + 0] = bf2f((u16)(p0.x));
            Ps[sn][pmc + 1] = bf2f((u16)(p0.x >> 16));
            Ps[sn][pmc + 2] = bf2f((u16)(p0.y));
            Ps[sn][pmc + 3] = bf2f((u16)(p0.y >> 16));
            Ps[sn][pmc + 4] = bf2f((u16)(p0.z));
            Ps[sn][pmc + 5] = bf2f((u16)(p0.z >> 16));
            Ps[sn][pmc + 6] = bf2f((u16)(p0.w));
            Ps[sn][pmc + 7] = bf2f((u16)(p0.w >> 16));
            Ps[sn][pmc + 8] = bf2f((u16)(p1.x));
            Ps[sn][pmc + 9] = bf2f((u16)(p1.x >> 16));
            Ps[sn][pmc + 10] = bf2f((u16)(p1.y));
            Ps[sn][pmc + 11] = bf2f((u16)(p1.y >> 16));
            Ps[sn][pmc + 12] = bf2f((u16)(p1.z));
            Ps[sn][pmc + 13] = bf2f((u16)(p1.z >> 16));
            Ps[sn][pmc + 14] = bf2f((u16)(p1.w));
            Ps[sn][pmc + 15] = bf2f((u16)(p1.w >> 16));
        }
        __syncthreads();
#pragma unroll 8
        for (int nn = 0; nn < 64; ++nn) {
            float a0 = Fs[nn][tl];
            float a1 = Fs[nn][tl + 1];
            float4 p4 = *(const float4*)&Ps[nn][tm];
            acc[0][0] = fmaf(a0, p4.x, acc[0][0]);
            acc[0][1] = fmaf(a0, p4.y, acc[0][1]);
            acc[0][2] = fmaf(a0, p4.z, acc[0][2]);
            acc[0][3] = fmaf(a0, p4.w, acc[0][3]);
            acc[1][0] = fmaf(a1, p4.x, acc[1][0]);
            acc[1][1] = fmaf(a1, p4.y, acc[1][1]);
            acc[1][2] = fmaf(a1, p4.z, acc[1][2]);
            acc[1][3] = fmaf(a1, p4.w, acc[1][3]);
        }
    }

#pragma unroll
    for (int i = 0; i < 2; ++i) {
        float* dst = agg + ((size_t)b * L_DIM + l0 + tl + i) * M_DIM + tm;
        *(float4*)dst = make_float4(acc[i][0], acc[i][1], acc[i][2], acc[i][3]);
    }
}

// ---------------------------------------------------------------------------
// Final normalization cascade. grid B, 256 thr.
// ---------------------------------------------------------------------------
__global__ __launch_bounds__(256) void final_kernel(const float* __restrict__ agg,
                                                    const float* __restrict__ tok,
                                                    float* __restrict__ out) {
    __shared__ __align__(16) float ag[L_DIM * M_DIM];
    __shared__ float rm[M_DIM];
    __shared__ float red[4];
    __shared__ float tk[G_DIM];
    const int b = blockIdx.x;
    const int tid = threadIdx.x;
    const int lane = tid & 63;
    const int wave = tid >> 6;
    const float EPS = 1e-12f;

    const float4* ab = (const float4*)(agg + (size_t)b * L_DIM * M_DIM);
    for (int e4 = tid; e4 < L_DIM * M_DIM / 4; e4 += 256) ((float4*)ag)[e4] = ab[e4];
    tk[tid] = tok[(size_t)b * G_DIM + tid];
    __syncthreads();

    if (tid < M_DIM) {
        float ss = 0.f;
#pragma unroll 8
        for (int l = 0; l < L_DIM; ++l) {
            float x = ag[l * M_DIM + tid];
            ss = fmaf(x, x, ss);
        }
        rm[tid] = 1.f / fmaxf(sqrtf(ss), EPS);
    }
    const float tv = tk[tid];
    float ssl = tv * tv;
    ssl = waveReduceSum(ssl);
    if (lane == 0) red[wave] = ssl;
    __syncthreads();
    const float stok = red[0] + red[1] + red[2] + red[3];
    const float rt = 1.f / fmaxf(sqrtf(stok), EPS);
    const float tn = tv * rt;

    float gs = tn * tn;
    for (int e = tid; e < L_DIM * M_DIM; e += 256) {
        float x = ag[e] * rm[e & (M_DIM - 1)];
        gs = fmaf(x, x, gs);
    }
    __syncthreads();
    gs = waveReduceSum(gs);
    if (lane == 0) red[wave] = gs;
    __syncthreads();
    const float G = red[0] + red[1] + red[2] + red[3];
    const float rg = 1.f / fmaxf(sqrtf(G), EPS);

    float* ob = out + (size_t)b * (G_DIM + L_DIM * M_DIM);
    ob[tid] = tn * rg;
    for (int e = tid; e < L_DIM * M_DIM; e += 256)
        ob[G_DIM + e] = ag[e] * rm[e & (M_DIM - 1)] * rg;
}

// ---------------------------------------------------------------------------
extern "C" void kernel_launch(void* const* d_in, const int* in_sizes, int n_in,
                              void* d_out, int out_size, void* d_ws, size_t ws_size,
                              hipStream_t stream) {
    const float* x    = (const float*)d_in[0];
    const float* t    = (const float*)d_in[1];
    const float* tw1  = (const float*)d_in[2];
    const float* tb1  = (const float*)d_in[3];
    const float* tw2  = (const float*)d_in[4];
    const float* tb2  = (const float*)d_in[5];
    const float* cw1  = (const float*)d_in[6];
    const float* cb1  = (const float*)d_in[7];
    const float* cw2  = (const float*)d_in[8];
    const float* cb2  = (const float*)d_in[9];
    const float* sw1  = (const float*)d_in[10];
    const float* sb1  = (const float*)d_in[11];
    const float* sw2  = (const float*)d_in[12];
    const float* sb2  = (const float*)d_in[13];
    const float* dust = (const float*)d_in[14];
    float* out = (float*)d_out;

    char* ws = (char*)d_ws;
    u16* xP    = (u16*)(ws);                         // 100,663,296
    u16* fT    = (u16*)(ws + 100663296ull);          //  16,777,216
    u16* pT    = (u16*)(ws + 117440512ull);          //   8,388,608
    u16* cw1p  = (u16*)(ws + 125829120ull);          //     786,432
    u16* sw1p  = (u16*)(ws + 126615552ull);          //     786,432
    u16* cw2p  = (u16*)(ws + 127401984ull);          //     131,072
    u16* sw2p  = (u16*)(ws + 127533056ull);          //      65,536
    float* hidb = (float*)(ws + 127598592ull);       //     131,072
    // reuse of dead xP region after fused12:
    u16* PTb      = (u16*)(ws);                      //   8,388,608 (bf16)
    float* tokbuf = (float*)(ws + 20971520ull);      //      65,536
    float* aggbuf = (float*)(ws + 25165824ull);      //   2,097,152

    prep_weights<<<432, 256, 0, stream>>>(cw1, sw1, cw2, sw2,
                                          cw1p, sw1p, cw2p, sw2p);
    transpose_x<<<dim3(N_LOC / 64, C_IN / 64, B_SZ), 256, 0, stream>>>(x, xP);

    fused12<<<dim3(8, 2, B_SZ), 512, 0, stream>>>(
        xP, cw1p, cb1, cw2p, cb2, sw1p, sb1, sw2p, sb2, fT, pT);

    tok1_kernel<<<dim3(HID / 64, B_SZ), 256, 0, stream>>>(t, tw1, tb1, hidb);
    tok2_kernel<<<dim3(G_DIM / 64, B_SZ), 256, 0, stream>>>(hidb, tw2, tb2, tokbuf);

    sinkhorn_kernel<<<B_SZ, 1024, 0, stream>>>(pT, dust, PTb);
    agg_kernel<<<dim3(L_DIM / 32, B_SZ), 256, 0, stream>>>(fT, PTb, aggbuf);
    final_kernel<<<B_SZ, 256, 0, stream>>>(aggbuf, tokbuf, out);
}